// Round 5
// baseline (172.378 us; speedup 1.0000x reference)
//
#include <hip/hip_runtime.h>

#define HH    1024
#define WW    1024
#define KS    15
#define PAD   7
#define CELL  256
#define BX    64            // x-width per block (4 waves x 16)
#define STRIP 128           // output rows per block
#define TROWS (STRIP + 2*PAD)   // 142
#define TCOLS 80            // staged halves per row (160B rows)
#define NJP   (STRIP / 16)  // 8 row-patches

typedef _Float16 f16x8 __attribute__((ext_vector_type(8)));
typedef _Float16 f16x4 __attribute__((ext_vector_type(4)));
typedef float    f32x4 __attribute__((ext_vector_type(4)));

__global__ __launch_bounds__(256, 7) void pb_mfma_kernel(
    const float* __restrict__ x,
    const float* __restrict__ kern,
    float* __restrict__ out)
{
    __shared__ __align__(16) _Float16 s_tile[TROWS * TCOLS];   // 22720 B (sole LDS use)

    const int tid  = threadIdx.x;
    const int lane = tid & 63;
    const int w    = tid >> 6;           // wave id: x sub-block
    const int g    = lane >> 4;          // k-group 0..3
    const int cc   = lane & 15;          // A-row / B-col index

    const int bx0   = blockIdx.x * BX;
    const int ci    = blockIdx.x >> 2;   // cell col
    const int strip = blockIdx.y & 1;
    const int cj    = blockIdx.y >> 1;   // cell row
    const int bc    = blockIdx.z;        // plane (b*c)

    const int cellx0 = ci * CELL, cellx1 = cellx0 + CELL - 1;
    const int celly0 = cj * CELL, celly1 = celly0 + CELL - 1;
    const int sy0    = celly0 + strip * STRIP;

    const float* plane = x + (size_t)bc * HH * WW;

    // ---- stage 142x80 f16 halo strip; window x = [bx0-8, bx0+71] (16B-aligned) ----
    {
        const int nG = TROWS * 20;       // float4 groups
        for (int idx = tid; idx < nG; idx += 256) {
            int row = idx / 20;
            int c4  = idx - row * 20;
            int gy  = min(max(sy0 - PAD + row, celly0), celly1);
            int gx0 = bx0 - 8 + 4 * c4;
            const float* src = plane + (size_t)gy * WW;
            float v0, v1, v2, v3;
            if (gx0 >= cellx0 && gx0 + 3 <= cellx1) {
                float4 v = *(const float4*)(src + gx0);
                v0 = v.x; v1 = v.y; v2 = v.z; v3 = v.w;
            } else {
                v0 = src[min(max(gx0 + 0, cellx0), cellx1)];
                v1 = src[min(max(gx0 + 1, cellx0), cellx1)];
                v2 = src[min(max(gx0 + 2, cellx0), cellx1)];
                v3 = src[min(max(gx0 + 3, cellx0), cellx1)];
            }
            f16x4 h;
            h[0] = (_Float16)v0; h[1] = (_Float16)v1;
            h[2] = (_Float16)v2; h[3] = (_Float16)v3;
            *(f16x4*)(s_tile + row * TCOLS + 4 * c4) = h;   // ds_write_b64
        }
    }

    // ---- per-wave kernel sum + inv (global reads, L1-resident; overlaps staging) ----
    const float* kp = kern + (cj * 4 + ci) * (KS * KS);
    float s = 0.f;
    for (int i = lane; i < KS * KS; i += 64) s += kp[i];
    #pragma unroll
    for (int m = 1; m < 64; m <<= 1) s += __shfl_xor(s, m, 64);
    const float inv = 1.0f / (s + 1e-12f);

    // ---- Toeplitz A fragments (shifted window): A[i][k] = kh[dy][k-i-1] ----
    // Lane layout: i = cc, k = 8g + e.
    f16x8 af[KS];
    #pragma unroll
    for (int dy = 0; dy < KS; ++dy) {
        f16x8 a;
        #pragma unroll
        for (int e = 0; e < 8; ++e) {
            int dx  = 8 * g + e - cc - 1;
            int dxc = min(max(dx, 0), KS - 1);
            float kv = kp[dy * KS + dxc] * inv;
            a[e] = (_Float16)((dx == dxc) ? kv : 0.f);
        }
        af[dy] = a;
    }

    __syncthreads();

    // ---- compute: 8 patches x 15 dy ----
    const _Float16* bbase = s_tile + cc * TCOLS + w * 16 + g * 8;
    float* oplane = out + (size_t)bc * HH * WW;

    #pragma unroll
    for (int jp = 0; jp < NJP; ++jp) {
        f32x4 acc0 = {0.f, 0.f, 0.f, 0.f};
        f32x4 acc1 = {0.f, 0.f, 0.f, 0.f};
        #pragma unroll
        for (int dy = 0; dy < KS; ++dy) {
            f16x8 b = *(const f16x8*)(bbase + (16 * jp + dy) * TCOLS);
            if (dy & 1)
                acc1 = __builtin_amdgcn_mfma_f32_16x16x32_f16(af[dy], b, acc1, 0, 0, 0);
            else
                acc0 = __builtin_amdgcn_mfma_f32_16x16x32_f16(af[dy], b, acc0, 0, 0, 0);
        }
        f32x4 r = acc0 + acc1;
        // D: col=lane&15 (image row), row=4*(lane>>4)+e (x position)
        float* op = oplane + (size_t)(sy0 + 16 * jp + cc) * WW + bx0 + 16 * w + 4 * g;
        *(f32x4*)op = r;
    }
}

extern "C" void kernel_launch(void* const* d_in, const int* in_sizes, int n_in,
                              void* d_out, int out_size, void* d_ws, size_t ws_size,
                              hipStream_t stream) {
    (void)in_sizes; (void)n_in; (void)d_ws; (void)ws_size; (void)out_size;
    const float* x    = (const float*)d_in[0];
    const float* kern = (const float*)d_in[1];
    float* out        = (float*)d_out;

    dim3 grid(WW / BX, 8, 8 * 3);   // 16 x-strips, 8 y-strips, 24 planes
    pb_mfma_kernel<<<grid, 256, 0, stream>>>(x, kern, out);
}

// Round 6
// 75.680 us; speedup vs baseline: 2.2777x; 2.2777x over previous
//
#include <hip/hip_runtime.h>

#define HH    1024
#define WW    1024
#define KS    15
#define PAD   7
#define CELL  256
#define BX    64            // x-width per block (4 waves x 16)
#define STRIP 128           // output rows per block
#define TROWS (STRIP + 2*PAD)   // 142
#define TCOLS 80            // staged halves per row (160B rows)
#define NJP   (STRIP / 16)  // 8 row-patches

typedef _Float16 f16x8 __attribute__((ext_vector_type(8)));
typedef _Float16 f16x4 __attribute__((ext_vector_type(4)));
typedef float    f32x4 __attribute__((ext_vector_type(4)));

// NOTE: no min-waves clause. R5's __launch_bounds__(256,7) forced VGPR=36 and
// spilled the 60-VGPR A-fragment array to scratch (WRITE_SIZE 98->297 MB).
// Compiler-chosen allocation (R4: 68 VGPR) holds af[15] without spill.
__global__ __launch_bounds__(256) void pb_mfma_kernel(
    const float* __restrict__ x,
    const float* __restrict__ kern,
    float* __restrict__ out)
{
    __shared__ __align__(16) _Float16 s_tile[TROWS * TCOLS];   // 22720 B (sole LDS use)

    const int tid  = threadIdx.x;
    const int lane = tid & 63;
    const int w    = tid >> 6;           // wave id: x sub-block
    const int g    = lane >> 4;          // k-group 0..3
    const int cc   = lane & 15;          // A-row / B-col index

    const int bx0   = blockIdx.x * BX;
    const int ci    = blockIdx.x >> 2;   // cell col
    const int strip = blockIdx.y & 1;
    const int cj    = blockIdx.y >> 1;   // cell row
    const int bc    = blockIdx.z;        // plane (b*c)

    const int cellx0 = ci * CELL, cellx1 = cellx0 + CELL - 1;
    const int celly0 = cj * CELL, celly1 = celly0 + CELL - 1;
    const int sy0    = celly0 + strip * STRIP;

    const float* plane = x + (size_t)bc * HH * WW;

    // ---- stage 142x80 f16 halo strip; window x = [bx0-8, bx0+71] (16B-aligned) ----
    {
        const int nG = TROWS * 20;       // float4 groups
        for (int idx = tid; idx < nG; idx += 256) {
            int row = idx / 20;
            int c4  = idx - row * 20;
            int gy  = min(max(sy0 - PAD + row, celly0), celly1);
            int gx0 = bx0 - 8 + 4 * c4;
            const float* src = plane + (size_t)gy * WW;
            float v0, v1, v2, v3;
            if (gx0 >= cellx0 && gx0 + 3 <= cellx1) {
                float4 v = *(const float4*)(src + gx0);
                v0 = v.x; v1 = v.y; v2 = v.z; v3 = v.w;
            } else {
                v0 = src[min(max(gx0 + 0, cellx0), cellx1)];
                v1 = src[min(max(gx0 + 1, cellx0), cellx1)];
                v2 = src[min(max(gx0 + 2, cellx0), cellx1)];
                v3 = src[min(max(gx0 + 3, cellx0), cellx1)];
            }
            f16x4 h;
            h[0] = (_Float16)v0; h[1] = (_Float16)v1;
            h[2] = (_Float16)v2; h[3] = (_Float16)v3;
            *(f16x4*)(s_tile + row * TCOLS + 4 * c4) = h;   // ds_write_b64
        }
    }

    // ---- per-wave kernel sum + inv (global reads, L1-resident; overlaps staging) ----
    const float* kp = kern + (cj * 4 + ci) * (KS * KS);
    float s = 0.f;
    for (int i = lane; i < KS * KS; i += 64) s += kp[i];
    #pragma unroll
    for (int m = 1; m < 64; m <<= 1) s += __shfl_xor(s, m, 64);
    const float inv = 1.0f / (s + 1e-12f);

    // ---- Toeplitz A fragments (shifted window): A[i][k] = kh[dy][k-i-1] ----
    // Lane layout: i = cc, k = 8g + e.
    f16x8 af[KS];
    #pragma unroll
    for (int dy = 0; dy < KS; ++dy) {
        f16x8 a;
        #pragma unroll
        for (int e = 0; e < 8; ++e) {
            int dx  = 8 * g + e - cc - 1;
            int dxc = min(max(dx, 0), KS - 1);
            float kv = kp[dy * KS + dxc] * inv;
            a[e] = (_Float16)((dx == dxc) ? kv : 0.f);
        }
        af[dy] = a;
    }

    __syncthreads();

    // ---- compute: 8 patches x 15 dy ----
    const _Float16* bbase = s_tile + cc * TCOLS + w * 16 + g * 8;
    float* oplane = out + (size_t)bc * HH * WW;

    #pragma unroll
    for (int jp = 0; jp < NJP; ++jp) {
        f32x4 acc0 = {0.f, 0.f, 0.f, 0.f};
        f32x4 acc1 = {0.f, 0.f, 0.f, 0.f};
        #pragma unroll
        for (int dy = 0; dy < KS; ++dy) {
            f16x8 b = *(const f16x8*)(bbase + (16 * jp + dy) * TCOLS);
            if (dy & 1)
                acc1 = __builtin_amdgcn_mfma_f32_16x16x32_f16(af[dy], b, acc1, 0, 0, 0);
            else
                acc0 = __builtin_amdgcn_mfma_f32_16x16x32_f16(af[dy], b, acc0, 0, 0, 0);
        }
        f32x4 r = acc0 + acc1;
        // D: col=lane&15 (image row), row=4*(lane>>4)+e (x position)
        float* op = oplane + (size_t)(sy0 + 16 * jp + cc) * WW + bx0 + 16 * w + 4 * g;
        *(f32x4*)op = r;
    }
}

extern "C" void kernel_launch(void* const* d_in, const int* in_sizes, int n_in,
                              void* d_out, int out_size, void* d_ws, size_t ws_size,
                              hipStream_t stream) {
    (void)in_sizes; (void)n_in; (void)d_ws; (void)ws_size; (void)out_size;
    const float* x    = (const float*)d_in[0];
    const float* kern = (const float*)d_in[1];
    float* out        = (float*)d_out;

    dim3 grid(WW / BX, 8, 8 * 3);   // 16 x-strips, 8 y-strips, 24 planes
    pb_mfma_kernel<<<grid, 256, 0, stream>>>(x, kern, out);
}

// Round 7
// 69.155 us; speedup vs baseline: 2.4926x; 1.0943x over previous
//
#include <hip/hip_runtime.h>

#define HH    1024
#define WW    1024
#define KS    15
#define PAD   7
#define CELL  256
#define BX    64            // x-width per block (4 waves x 16)
#define STRIP 128           // output rows per block
#define TROWS (STRIP + 2*PAD)   // 142
#define TCOLS 80            // staged halves per row (160B rows)
#define NJP   (STRIP / 16)  // 8 row-patches
#define NGRP  (TROWS * 20)  // 2840 float4 groups

typedef _Float16     f16x8 __attribute__((ext_vector_type(8)));
typedef _Float16     f16x4 __attribute__((ext_vector_type(4)));
typedef float        f32x4 __attribute__((ext_vector_type(4)));
typedef unsigned int u32x4 __attribute__((ext_vector_type(4)));

// __launch_bounds__(256,4): VGPR cap 128 (4 waves/SIMD x 128 = full 512-reg file).
// R5 showed cap 36 -> spills; R6 showed no cap -> compiler picked 44 VGPR and
// REMATERIALIZED the 60-VGPR af[] inside the jp loop (960 global loads/thread).
__global__ __launch_bounds__(256, 4) void pb_mfma_kernel(
    const float* __restrict__ x,
    const float* __restrict__ kern,
    float* __restrict__ out)
{
    __shared__ __align__(16) _Float16 s_tile[TROWS * TCOLS];   // 22720 B (sole LDS use)

    const int tid  = threadIdx.x;
    const int lane = tid & 63;
    const int w    = tid >> 6;           // wave id: x sub-block
    const int g    = lane >> 4;          // k-group 0..3
    const int cc   = lane & 15;          // A-row / B-col index

    const int bx0   = blockIdx.x * BX;
    const int ci    = blockIdx.x >> 2;   // cell col
    const int strip = blockIdx.y & 1;
    const int cj    = blockIdx.y >> 1;   // cell row
    const int bc    = blockIdx.z;        // plane (b*c)

    const int cellx0 = ci * CELL, cellx1 = cellx0 + CELL - 1;
    const int celly0 = cj * CELL, celly1 = celly0 + CELL - 1;
    const int sy0    = celly0 + strip * STRIP;

    const float* plane = x + (size_t)bc * HH * WW;

    // ---- branchless staging: clamped-aligned float4 + edge broadcast selects ----
    // Group x-window [gx0, gx0+3] with gx0 = bx0-8+4*c4; since bx0,cellx0 = 0 mod 4,
    // each group is entirely inside the cell, entirely left, or entirely right.
    auto stage_group = [&](int idx) {
        int row  = idx / 20;
        int c4   = idx - row * 20;
        int gy   = min(max(sy0 - PAD + row, celly0), celly1);
        int gx0  = bx0 - 8 + 4 * c4;
        int gx0c = min(max(gx0, cellx0), cellx0 + CELL - 4);   // aligned, in-bounds
        float4 v = *(const float4*)(plane + (size_t)gy * WW + gx0c);
        bool lo = gx0 <  cellx0;              // whole group left of cell -> v.x
        bool hi = gx0 >  cellx0 + CELL - 4;   // whole group right of cell -> v.w
        float e0 = hi ? v.w : v.x;
        float e1 = lo ? v.x : (hi ? v.w : v.y);
        float e2 = lo ? v.x : (hi ? v.w : v.z);
        float e3 = lo ? v.x : v.w;
        f16x4 h;
        h[0] = (_Float16)e0; h[1] = (_Float16)e1;
        h[2] = (_Float16)e2; h[3] = (_Float16)e3;
        *(f16x4*)(s_tile + row * TCOLS + 4 * c4) = h;   // ds_write_b64
    };
    #pragma unroll
    for (int i = 0; i < 11; ++i) stage_group(tid + 256 * i);
    if (tid < NGRP - 256 * 11) stage_group(256 * 11 + tid);

    // ---- per-wave kernel sum + inv (global, L2-resident; overlaps staging) ----
    const float* kp = kern + (cj * 4 + ci) * (KS * KS);
    float s = 0.f;
    #pragma unroll
    for (int i = 0; i < 4; ++i) {
        int t = lane + 64 * i;
        s += (t < KS * KS) ? kp[t] : 0.f;
    }
    #pragma unroll
    for (int m = 1; m < 64; m <<= 1) s += __shfl_xor(s, m, 64);
    const float inv = 1.0f / (s + 1e-12f);

    // ---- Toeplitz A fragments: A[i][k] = kh[dy][k-i-1], i=cc, k=8g+e ----
    u32x4 af[KS];
    #pragma unroll
    for (int dy = 0; dy < KS; ++dy) {
        f16x8 a;
        #pragma unroll
        for (int e = 0; e < 8; ++e) {
            int dx  = 8 * g + e - cc - 1;
            int dxc = min(max(dx, 0), KS - 1);
            float kv = kp[dy * KS + dxc] * inv;
            a[e] = (_Float16)((dx == dxc) ? kv : 0.f);
        }
        af[dy] = __builtin_bit_cast(u32x4, a);
    }
    // Pin af in registers: forbid rematerialization inside the jp loop.
    #pragma unroll
    for (int dy = 0; dy < KS; ++dy)
        asm volatile("" : "+v"(af[dy]));

    __syncthreads();

    // ---- compute: 8 patches x 15 dy ----
    const _Float16* bbase = s_tile + cc * TCOLS + w * 16 + g * 8;
    float* oplane = out + (size_t)bc * HH * WW;

    #pragma unroll
    for (int jp = 0; jp < NJP; ++jp) {
        f32x4 acc0 = {0.f, 0.f, 0.f, 0.f};
        f32x4 acc1 = {0.f, 0.f, 0.f, 0.f};
        #pragma unroll
        for (int dy = 0; dy < KS; ++dy) {
            f16x8 b = *(const f16x8*)(bbase + (16 * jp + dy) * TCOLS);
            if (dy & 1)
                acc1 = __builtin_amdgcn_mfma_f32_16x16x32_f16(
                           __builtin_bit_cast(f16x8, af[dy]), b, acc1, 0, 0, 0);
            else
                acc0 = __builtin_amdgcn_mfma_f32_16x16x32_f16(
                           __builtin_bit_cast(f16x8, af[dy]), b, acc0, 0, 0, 0);
        }
        f32x4 r = acc0 + acc1;
        // D: col=lane&15 (image row), row=4*(lane>>4)+e (x position)
        float* op = oplane + (size_t)(sy0 + 16 * jp + cc) * WW + bx0 + 16 * w + 4 * g;
        *(f32x4*)op = r;
    }
}

extern "C" void kernel_launch(void* const* d_in, const int* in_sizes, int n_in,
                              void* d_out, int out_size, void* d_ws, size_t ws_size,
                              hipStream_t stream) {
    (void)in_sizes; (void)n_in; (void)d_ws; (void)ws_size; (void)out_size;
    const float* x    = (const float*)d_in[0];
    const float* kern = (const float*)d_in[1];
    float* out        = (float*)d_out;

    dim3 grid(WW / BX, 8, 8 * 3);   // 16 x-strips, 8 y-strips, 24 planes
    pb_mfma_kernel<<<grid, 256, 0, stream>>>(x, kern, out);
}

// Round 8
// 65.458 us; speedup vs baseline: 2.6334x; 1.0565x over previous
//
#include <hip/hip_runtime.h>

#define HH    1024
#define WW    1024
#define KS    15
#define PAD   7
#define CELL  256
#define BX    64            // x-width per block (4 waves x 16)
#define STRIP 128           // output rows per block
#define TROWS (STRIP + 2*PAD)   // 142
#define TCOLS 80            // staged halves per row (160B rows)
#define NJP   (STRIP / 16)  // 8 row-patches
#define NGRP  (TROWS * 20)  // 2840 float4 groups
#define AWS_CELL_BYTES (KS * 1024)   // 15 fragments x 1KB

typedef _Float16     f16x8 __attribute__((ext_vector_type(8)));
typedef _Float16     f16x4 __attribute__((ext_vector_type(4)));
typedef float        f32x4 __attribute__((ext_vector_type(4)));
typedef unsigned int u32x4 __attribute__((ext_vector_type(4)));

// ---- prep: materialize normalized Toeplitz A fragments per cell into d_ws ----
// Layout: u32 word  cell*3840 + dy*256 + t,  t = i*16 + k2  (i = x-pos row 0..15,
// halves k = 2*k2, 2*k2+1).  Main lane (g,cc) then loads words cc*16+4g..+3
// = bytes dy*1024 + cc*64 + g*16: one coalesced dwordx4 per lane.
__global__ __launch_bounds__(256) void pb_prep_kernel(
    const float* __restrict__ kern, unsigned int* __restrict__ aws)
{
    const int cell = blockIdx.x;           // cj*4+ci, matches main indexing
    const int tid  = threadIdx.x;
    const int lane = tid & 63;
    const float* kp = kern + cell * (KS * KS);

    float s = 0.f;
    #pragma unroll
    for (int i = 0; i < 4; ++i) {
        int t = lane + 64 * i;
        s += (t < KS * KS) ? kp[t] : 0.f;
    }
    #pragma unroll
    for (int m = 1; m < 64; m <<= 1) s += __shfl_xor(s, m, 64);
    const float inv = 1.0f / (s + 1e-12f);

    const int i  = tid >> 4;               // x-position (A row)
    const int k2 = tid & 15;               // half-pair index
    unsigned int* wp = aws + cell * (AWS_CELL_BYTES / 4) + tid;

    for (int dy = 0; dy < KS; ++dy) {
        float v0 = 0.f, v1 = 0.f;
        int dx0 = 2 * k2 - i - 1;          // A[i][k] = kh[k-i-1]
        int dx1 = dx0 + 1;
        if (dx0 >= 0 && dx0 < KS) v0 = kp[dy * KS + dx0] * inv;
        if (dx1 >= 0 && dx1 < KS) v1 = kp[dy * KS + dx1] * inv;
        f16x4 h; h[0] = (_Float16)v0; h[1] = (_Float16)v1; h[2] = 0; h[3] = 0;
        unsigned long long u = __builtin_bit_cast(unsigned long long, h);
        wp[dy * 256] = (unsigned int)u;    // low 2 halves
    }
}

// ---- main ----
__global__ __launch_bounds__(256, 4) void pb_mfma_kernel(
    const float* __restrict__ x,
    const unsigned int* __restrict__ aws,
    float* __restrict__ out)
{
    __shared__ __align__(16) _Float16 s_tile[TROWS * TCOLS];   // 22720 B (sole LDS use)

    const int tid  = threadIdx.x;
    const int lane = tid & 63;
    const int w    = tid >> 6;           // wave id: x sub-block
    const int g    = lane >> 4;          // k-group 0..3
    const int cc   = lane & 15;          // A-row / B-col index

    const int bx0   = blockIdx.x * BX;
    const int ci    = blockIdx.x >> 2;   // cell col
    const int strip = blockIdx.y & 1;
    const int cj    = blockIdx.y >> 1;   // cell row
    const int bc    = blockIdx.z;        // plane (b*c)

    const int cellx0 = ci * CELL;
    const int celly0 = cj * CELL, celly1 = celly0 + CELL - 1;
    const int sy0    = celly0 + strip * STRIP;

    const float* plane = x + (size_t)bc * HH * WW;

    // ---- A fragments: 15 coalesced dwordx4 loads from prep output ----
    const u32x4* ap = (const u32x4*)(aws + (cj * 4 + ci) * (AWS_CELL_BYTES / 4))
                      + cc * 4 + g;      // + dy*64 per fragment
    u32x4 af[KS];
    #pragma unroll
    for (int dy = 0; dy < KS; ++dy) af[dy] = ap[dy * 64];
    #pragma unroll
    for (int dy = 0; dy < KS; ++dy) asm volatile("" : "+v"(af[dy]));

    // ---- branchless staging: clamped-aligned float4 + edge broadcast selects ----
    auto stage_group = [&](int idx) {
        int row  = idx / 20;
        int c4   = idx - row * 20;
        int gy   = min(max(sy0 - PAD + row, celly0), celly1);
        int gx0  = bx0 - 8 + 4 * c4;
        int gx0c = min(max(gx0, cellx0), cellx0 + CELL - 4);
        float4 v = *(const float4*)(plane + (size_t)gy * WW + gx0c);
        bool lo = gx0 <  cellx0;
        bool hi = gx0 >  cellx0 + CELL - 4;
        float e0 = hi ? v.w : v.x;
        float e1 = lo ? v.x : (hi ? v.w : v.y);
        float e2 = lo ? v.x : (hi ? v.w : v.z);
        float e3 = lo ? v.x : v.w;
        f16x4 h;
        h[0] = (_Float16)e0; h[1] = (_Float16)e1;
        h[2] = (_Float16)e2; h[3] = (_Float16)e3;
        *(f16x4*)(s_tile + row * TCOLS + 4 * c4) = h;
    };
    #pragma unroll
    for (int i = 0; i < 11; ++i) stage_group(tid + 256 * i);
    if (tid < NGRP - 256 * 11) stage_group(256 * 11 + tid);

    __syncthreads();

    // ---- compute: 8 patches x 15 dy ----
    const _Float16* bbase = s_tile + cc * TCOLS + w * 16 + g * 8;
    float* oplane = out + (size_t)bc * HH * WW;

    #pragma unroll
    for (int jp = 0; jp < NJP; ++jp) {
        f32x4 acc0 = {0.f, 0.f, 0.f, 0.f};
        f32x4 acc1 = {0.f, 0.f, 0.f, 0.f};
        #pragma unroll
        for (int dy = 0; dy < KS; ++dy) {
            f16x8 b = *(const f16x8*)(bbase + (16 * jp + dy) * TCOLS);
            if (dy & 1)
                acc1 = __builtin_amdgcn_mfma_f32_16x16x32_f16(
                           __builtin_bit_cast(f16x8, af[dy]), b, acc1, 0, 0, 0);
            else
                acc0 = __builtin_amdgcn_mfma_f32_16x16x32_f16(
                           __builtin_bit_cast(f16x8, af[dy]), b, acc0, 0, 0, 0);
        }
        f32x4 r = acc0 + acc1;
        // D: col=lane&15 (image row), row=4*(lane>>4)+e (x position)
        float* op = oplane + (size_t)(sy0 + 16 * jp + cc) * WW + bx0 + 16 * w + 4 * g;
        *(f32x4*)op = r;
    }
}

extern "C" void kernel_launch(void* const* d_in, const int* in_sizes, int n_in,
                              void* d_out, int out_size, void* d_ws, size_t ws_size,
                              hipStream_t stream) {
    (void)in_sizes; (void)n_in; (void)ws_size; (void)out_size;
    const float* x    = (const float*)d_in[0];
    const float* kern = (const float*)d_in[1];
    float* out        = (float*)d_out;
    unsigned int* aws = (unsigned int*)d_ws;   // 16 cells x 15 KiB = 240 KiB

    pb_prep_kernel<<<16, 256, 0, stream>>>(kern, aws);
    dim3 grid(WW / BX, 8, 8 * 3);   // 16 x-strips, 8 y-strips, 24 planes
    pb_mfma_kernel<<<grid, 256, 0, stream>>>(x, aws, out);
}